// Round 4
// baseline (925.972 us; speedup 1.0000x reference)
//
#include <hip/hip_runtime.h>
#include <hip/hip_bf16.h>
#include <math.h>

typedef __bf16 bf16;
typedef __bf16 bf16x8 __attribute__((ext_vector_type(8)));
typedef float f32x4 __attribute__((ext_vector_type(4)));

#define MFMA(a, b, c) __builtin_amdgcn_mfma_f32_16x16x32_bf16((a), (b), (c), 0, 0, 0)

// async global->LDS, 16B per lane. LDS dest must be wave-uniform base + lane*16.
static __device__ __forceinline__ void gl16(const bf16* g, bf16* l) {
  __builtin_amdgcn_global_load_lds(
      (const __attribute__((address_space(1))) void*)g,
      (__attribute__((address_space(3))) void*)l, 16, 0, 0);
}

static __device__ __forceinline__ bf16x8 bzero8() {
  bf16x8 v;
#pragma unroll
  for (int i = 0; i < 8; ++i) v[i] = (bf16)0.0f;
  return v;
}

// ---------- W (K x N fp32, row-major) -> Wt (N x K bf16, row-major) ----------
// PERM=1: output row p takes orig W1 column (p>>8)*128 + (p&127) + ((p>>7)&1)*4096
// so each 256-row group pairs u-cols [b*128,+128) with g-cols [4096+b*128,+128).
template <int PERM>
__global__ void k_transpose_cvt(const float* __restrict__ W, bf16* __restrict__ Wt,
                                int K, int N) {
  __shared__ float tile[32][33];
  int k0 = blockIdx.x * 32, n0 = blockIdx.y * 32;
  int src_n0 = PERM ? (((n0 >> 8) << 7) + (n0 & 127) + (((n0 >> 7) & 1) << 12)) : n0;
  int tx = threadIdx.x & 31, ty = threadIdx.x >> 5;
  for (int i = ty; i < 32; i += 8)
    tile[i][tx] = W[(size_t)(k0 + i) * N + (src_n0 + tx)];
  __syncthreads();
  for (int i = ty; i < 32; i += 8)
    Wt[(size_t)(n0 + i) * K + (k0 + tx)] = (bf16)tile[tx][i];
}

// ---------- V (rows x 1024 bf16, token-major) -> Vt[b][h][d][kvpad] ----------
__global__ void k_transpose_v(const bf16* __restrict__ V, bf16* __restrict__ Vt,
                              int rows, int kvpad) {
  __shared__ __attribute__((aligned(16))) bf16 tile[64][72];
  int t0 = blockIdx.x * 64, h = blockIdx.y, b = blockIdx.z;
  int t = threadIdx.x;
  int tr = t >> 2, c0 = (t & 3) * 16;
  int token = t0 + tr;
  bf16x8 a = bzero8(), bv = bzero8();
  if (token < rows) {
    const bf16* src = V + ((size_t)(b * rows + token)) * 1024 + h * 64 + c0;
    a = *(const bf16x8*)src;
    bv = *(const bf16x8*)(src + 8);
  }
  *(bf16x8*)&tile[tr][c0] = a;
  *(bf16x8*)&tile[tr][c0 + 8] = bv;
  __syncthreads();
  int d = t >> 2, tq = (t & 3) * 16;
  bf16x8 o1, o2;
#pragma unroll
  for (int i = 0; i < 8; ++i) { o1[i] = tile[tq + i][d]; o2[i] = tile[tq + 8 + i][d]; }
  bf16* dst = Vt + ((size_t)((b * 16 + h) * 64 + d)) * kvpad + t0 + tq;
  *(bf16x8*)dst = o1;
  *(bf16x8*)(dst + 8) = o2;
}

// ---------- fp32 -> bf16 flat convert ----------
__global__ void k_cvt(const float* __restrict__ in, bf16* __restrict__ out, int n) {
  int i = blockIdx.x * 256 + threadIdx.x;
  if (i < n) out[i] = (bf16)in[i];
}

// ---------- LayerNorm over D=1024, one block per row, bf16 out ----------
__global__ void k_layernorm(const float* __restrict__ x, const float* __restrict__ g,
                            const float* __restrict__ b, bf16* __restrict__ out) {
  int row = blockIdx.x;
  float4 v = ((const float4*)(x + (size_t)row * 1024))[threadIdx.x];
  float s = v.x + v.y + v.z + v.w;
  float ss = v.x * v.x + v.y * v.y + v.z * v.z + v.w * v.w;
#pragma unroll
  for (int off = 1; off < 64; off <<= 1) {
    s += __shfl_xor(s, off);
    ss += __shfl_xor(ss, off);
  }
  __shared__ float sm[4], sm2[4];
  int w = threadIdx.x >> 6;
  if ((threadIdx.x & 63) == 0) { sm[w] = s; sm2[w] = ss; }
  __syncthreads();
  s = sm[0] + sm[1] + sm[2] + sm[3];
  ss = sm2[0] + sm2[1] + sm2[2] + sm2[3];
  float mu = s * (1.0f / 1024.0f);
  float var = ss * (1.0f / 1024.0f) - mu * mu;
  float rs = rsqrtf(var + 1e-5f);
  float4 gg = ((const float4*)g)[threadIdx.x];
  float4 bb = ((const float4*)b)[threadIdx.x];
  bf16* o = out + (size_t)row * 1024 + threadIdx.x * 4;
  o[0] = (bf16)((v.x - mu) * rs * gg.x + bb.x);
  o[1] = (bf16)((v.y - mu) * rs * gg.y + bb.y);
  o[2] = (bf16)((v.z - mu) * rs * gg.z + bb.z);
  o[3] = (bf16)((v.w - mu) * rs * gg.w + bb.w);
}

// ---------- GEMM: C[M,N] = A[M,K] @ Bt[N,K]^T  (128x128, m97 structure) ----------
template <int EPI>
__global__ __launch_bounds__(256, 2)
void k_gemm_bt(const bf16* __restrict__ A, const bf16* __restrict__ Bt,
               const float* __restrict__ bias, const float* __restrict__ res,
               void* __restrict__ Cp, int M, int N, int K) {
  __shared__ __attribute__((aligned(16))) bf16 As[128 * 32];
  __shared__ __attribute__((aligned(16))) bf16 Bs[128 * 32];
  int m0 = blockIdx.x * 128, n0 = blockIdx.y * 128;
  int tid = threadIdx.x, lane = tid & 63, wave = tid >> 6;
  int wm = (wave >> 1) * 64, wn = (wave & 1) * 64;
  int quad = lane >> 4, l15 = lane & 15;
  f32x4 acc[4][4];
#pragma unroll
  for (int i = 0; i < 4; ++i)
#pragma unroll
    for (int j = 0; j < 4; ++j)
#pragma unroll
      for (int r = 0; r < 4; ++r) acc[i][j][r] = 0.0f;
  int srow = wave * 16 + (lane >> 2), scol = (lane & 3) * 8;
  const bf16* ga = A + (size_t)(m0 + srow) * K + scol;
  const bf16* gb = Bt + (size_t)(n0 + srow) * K + scol;
  bf16* la = As + srow * 32 + scol;
  bf16* lb = Bs + srow * 32 + scol;
  for (int k0 = 0; k0 < K; k0 += 32) {
    gl16(ga, la);
    gl16(ga + (size_t)64 * K, la + 64 * 32);
    gl16(gb, lb);
    gl16(gb + (size_t)64 * K, lb + 64 * 32);
    ga += 32; gb += 32;
    __syncthreads();
    bf16x8 af[4], bfr[4];
#pragma unroll
    for (int i = 0; i < 4; ++i) af[i] = *(const bf16x8*)(&As[(wm + i * 16 + l15) * 32 + quad * 8]);
#pragma unroll
    for (int i = 0; i < 4; ++i) bfr[i] = *(const bf16x8*)(&Bs[(wn + i * 16 + l15) * 32 + quad * 8]);
#pragma unroll
    for (int mi = 0; mi < 4; ++mi)
#pragma unroll
      for (int ni = 0; ni < 4; ++ni)
        acc[mi][ni] = MFMA(af[mi], bfr[ni], acc[mi][ni]);
    __syncthreads();
  }
#pragma unroll
  for (int mi = 0; mi < 4; ++mi) {
#pragma unroll
    for (int r = 0; r < 4; ++r) {
      int row = m0 + wm + mi * 16 + quad * 4 + r;
      if (row >= M) continue;
#pragma unroll
      for (int ni = 0; ni < 4; ++ni) {
        int col = n0 + wn + ni * 16 + l15;
        float v = acc[mi][ni][r];
        if (EPI == 0) {
          ((bf16*)Cp)[(size_t)row * N + col] = (bf16)v;
        } else {
          ((float*)Cp)[(size_t)row * N + col] =
              v + bias[col] + res[(size_t)row * N + col];
        }
      }
    }
  }
}

// ---------- 256x256 8-phase GEMM (T2+T3+T4+T5, m201 template) ----------
// 512 thr = 8 waves (2M x 4N), BK=64, per-wave C = 128x64 (acc[8][4]).
// LDS 128KB: {A,B} x 2 slots x 2 halves x [128][64] bf16, st_16x32 swizzle
// (col_elem ^= (row&4)<<2; staged via linear gl16 dest + inverse-swizzled
// global source, rule #21; read swizzle folds to lane constant (l15&4)<<2).
// Phase q8=0..7 per iter (2 K-tiles): ds_read quadrant frags (12 on q8=0/4,
// else 4) -> stage half-tile H=p+7 -> [vmcnt(6) at q8=3/7; vmcnt(0) at the
// last tile] -> s_barrier -> lgkmcnt(0)+sched_barrier -> setprio(1) 16 MFMA
// setprio(0) -> s_barrier. Queue invariant: at each wait 14 loads out ->
// 6 remain (3 newest halves) => consumed tile fully landed (T4, m135).
// EPI 0: bf16 out scattered to consecutive [M][1024] segment buffers (QKV).
// EPI 1: GeGLU epilogue, permuted W1t: block cols 0-127=u, 128-255=g;
//        g-waves gelu -> 64KB LDS exchange -> u-waves write u*gelu(g).
template <int EPI>
__global__ __launch_bounds__(512, 2)
void k_gemm256(const bf16* __restrict__ A, const bf16* __restrict__ Bt,
               const float* __restrict__ b1, void* __restrict__ Cp,
               int M, int K) {
  __shared__ __attribute__((aligned(16))) bf16 As[2][2][128 * 64];
  __shared__ __attribute__((aligned(16))) bf16 Bs[2][2][128 * 64];
  int m0 = blockIdx.x * 256, n0 = blockIdx.y * 256;
  int tid = threadIdx.x, lane = tid & 63, wave = tid >> 6;
  int wr = wave >> 2, wc = wave & 3;
  int quad = lane >> 4, l15 = lane & 15;
  int rsw = (l15 & 4) << 2;  // read-side swizzle, constant per lane
  f32x4 acc[8][4];
#pragma unroll
  for (int i = 0; i < 8; ++i)
#pragma unroll
    for (int j = 0; j < 4; ++j)
#pragma unroll
      for (int r = 0; r < 4; ++r) acc[i][j][r] = 0.0f;
  // staging: thread covers rows {srow, srow+64} of a [128][64] half-tile,
  // 16B per round, LDS-linear dest, source col inverse-swizzled.
  int srow = tid >> 3;
  int scol = ((tid & 7) * 8) ^ ((srow & 4) << 2);
  int t8 = tid * 8;  // elems
  const bf16* gA = A + (size_t)(m0 + srow) * K + scol;
  const bf16* gB = Bt + (size_t)(n0 + srow) * K + scol;
  const int NT = K >> 6;
  auto stageHalf = [&](int h) {
    int tile = h >> 2, c = h & 3, slot = tile & 1;
    int k0 = tile << 6;
    if (c < 2) {  // B halves first (freed earliest by consume order)
      const bf16* s = gB + (size_t)(c * 128) * K + k0;
      gl16(s, &Bs[slot][c][t8]);
      gl16(s + (size_t)64 * K, &Bs[slot][c][4096 + t8]);
    } else {
      const bf16* s = gA + (size_t)((c - 2) * 128) * K + k0;
      gl16(s, &As[slot][c - 2][t8]);
      gl16(s + (size_t)64 * K, &As[slot][c - 2][4096 + t8]);
    }
  };
  // prologue: tile0 (4 halves) + tile1 {B0,B1,A0}; drain tile0 (14 -> 6 loads)
#pragma unroll
  for (int h = 0; h < 7; ++h) stageHalf(h);
  asm volatile("s_waitcnt vmcnt(6)" ::: "memory");
  asm volatile("s_barrier" ::: "memory");

  bf16x8 bfr[4][2];
  int NTh = NT >> 1;
  for (int t = 0; t < NTh; ++t) {
#pragma unroll
    for (int q8 = 0; q8 < 8; ++q8) {
      const int slot = q8 >> 2, q = q8 & 3;
      const bf16* Ah = &As[slot][wr][0];
      const bf16* Bh = &Bs[slot][wc >> 1][0];
      bf16x8 afr[2][2];
#pragma unroll
      for (int m2 = 0; m2 < 2; ++m2)
#pragma unroll
        for (int kk = 0; kk < 2; ++kk)
          afr[m2][kk] = *(const bf16x8*)&Ah[((q * 2 + m2) * 16 + l15) * 64 +
                                            ((kk * 32 + quad * 8) ^ rsw)];
      if (q == 0) {
#pragma unroll
        for (int ni = 0; ni < 4; ++ni)
#pragma unroll
          for (int kk = 0; kk < 2; ++kk)
            bfr[ni][kk] = *(const bf16x8*)&Bh[((wc & 1) * 64 + ni * 16 + l15) * 64 +
                                              ((kk * 32 + quad * 8) ^ rsw)];
      }
      int H = t * 8 + q8 + 7;
      if (H < 4 * NT) stageHalf(H);
      asm volatile("s_barrier" ::: "memory");
      asm volatile("s_waitcnt lgkmcnt(0)" ::: "memory");
      __builtin_amdgcn_sched_barrier(0);
      __builtin_amdgcn_s_setprio(1);
#pragma unroll
      for (int m2 = 0; m2 < 2; ++m2)
#pragma unroll
        for (int ni = 0; ni < 4; ++ni) {
          acc[q * 2 + m2][ni] = MFMA(afr[m2][0], bfr[ni][0], acc[q * 2 + m2][ni]);
          acc[q * 2 + m2][ni] = MFMA(afr[m2][1], bfr[ni][1], acc[q * 2 + m2][ni]);
        }
      __builtin_amdgcn_s_setprio(0);
      if (q == 3) {  // once per K-tile, before the barrier gating next reads
        if (t * 8 + q8 == 4 * NT - 5)
          asm volatile("s_waitcnt vmcnt(0)" ::: "memory");
        else
          asm volatile("s_waitcnt vmcnt(6)" ::: "memory");
      }
      asm volatile("s_barrier" ::: "memory");
    }
  }
  if (EPI == 0) {
    int seg = n0 >> 10;  // block's 256-col span never crosses a 1024 boundary
    int cl0 = (n0 & 1023) + wc * 64;
    bf16* outp = (bf16*)Cp + (size_t)seg * M * 1024;
#pragma unroll
    for (int mi = 0; mi < 8; ++mi)
#pragma unroll
      for (int r = 0; r < 4; ++r) {
        int row = m0 + wr * 128 + mi * 16 + quad * 4 + r;
#pragma unroll
        for (int ni = 0; ni < 4; ++ni)
          outp[(size_t)row * 1024 + cl0 + ni * 16 + l15] = (bf16)acc[mi][ni][r];
      }
  } else {
    bf16* Xg = &As[0][0][0];  // 256x128 bf16 = 64KB (pipeline done; reuse As)
    int cb = blockIdx.y * 128;
    if (wc >= 2) {  // g-waves: bias + gelu -> LDS
      int gc0 = (wc - 2) * 64;
#pragma unroll
      for (int mi = 0; mi < 8; ++mi)
#pragma unroll
        for (int ni = 0; ni < 4; ++ni) {
          int col = gc0 + ni * 16 + l15;
          float bg = b1[4096 + cb + col];
#pragma unroll
          for (int r = 0; r < 4; ++r) {
            int rowl = wr * 128 + mi * 16 + quad * 4 + r;
            float g = acc[mi][ni][r] + bg;
            float ge = 0.5f * g * (1.0f + erff(g * 0.70710678118654752f));
            Xg[rowl * 128 + col] = (bf16)ge;
          }
        }
    }
    __syncthreads();
    if (wc < 2) {  // u-waves: u * gelu(g) -> global
      int uc0 = wc * 64;
      bf16* Hg = (bf16*)Cp;
#pragma unroll
      for (int mi = 0; mi < 8; ++mi)
#pragma unroll
        for (int ni = 0; ni < 4; ++ni) {
          int col = uc0 + ni * 16 + l15;
          float bu = b1[cb + col];
#pragma unroll
          for (int r = 0; r < 4; ++r) {
            int rowl = wr * 128 + mi * 16 + quad * 4 + r;
            float u = acc[mi][ni][r] + bu;
            float hv = u * (float)Xg[rowl * 128 + col];
            Hg[(size_t)(m0 + rowl) * 4096 + cb + col] = (bf16)hv;
          }
        }
    }
  }
}

// ---------- Flash attention: 64 q-rows/block, 64-key chunks, pre-transposed V --
#define CSC 0.18033688011112042f /* 0.125 * log2(e) */
__global__ __launch_bounds__(256, 4)
void k_flash(const bf16* __restrict__ Q, const bf16* __restrict__ Kb,
             const bf16* __restrict__ VtG, bf16* __restrict__ O,
             int Sq, int Sk, int kvrows, int kvpad) {
  __shared__ __attribute__((aligned(16))) bf16 Ks[2][64 * 64];
  __shared__ __attribute__((aligned(16))) bf16 Vs[2][64 * 64];  // Vs[d][key]
  __shared__ __attribute__((aligned(16))) bf16 Ps[4][16 * 64];
  int qt = blockIdx.x, h = blockIdx.y, b = blockIdx.z;
  int tid = threadIdx.x, lane = tid & 63, wave = tid >> 6;
  int quad = lane >> 4, l15 = lane & 15;
  const bf16* qsrc = Q + (size_t)(b * Sq + qt * 64 + wave * 16 + l15) * 1024 + h * 64 + quad * 8;
  bf16x8 aq0 = *(const bf16x8*)qsrc;
  bf16x8 aq1 = *(const bf16x8*)(qsrc + 32);
  bf16x8 ones8;
#pragma unroll
  for (int i = 0; i < 8; ++i) ones8[i] = (bf16)1.0f;

  float m_r[4], l_r[4];
  f32x4 acc_o[4];
#pragma unroll
  for (int r = 0; r < 4; ++r) { m_r[r] = -1e30f; l_r[r] = 0.0f; }
#pragma unroll
  for (int ni = 0; ni < 4; ++ni)
#pragma unroll
    for (int r = 0; r < 4; ++r) acc_o[ni][r] = 0.0f;

  int srow = tid >> 3;
  int scol = ((tid & 7) * 8) ^ ((srow & 7) << 3);
  const bf16* kg0 = Kb + (size_t)(b * kvrows + srow) * 1024 + h * 64 + scol;
  const bf16* vg0 = VtG + ((size_t)((b * 16 + h) * 64 + srow)) * kvpad + scol;

  int nt = (Sk + 63) >> 6;
  {
    gl16(kg0, &Ks[0][tid * 8]);
    gl16(kg0 + (size_t)32 * 1024, &Ks[0][2048 + tid * 8]);
    gl16(vg0, &Vs[0][tid * 8]);
    gl16(vg0 + (size_t)32 * kvpad, &Vs[0][2048 + tid * 8]);
  }
  __syncthreads();

  int cur = 0;
  for (int t = 0; t < nt; ++t) {
    int k0 = t << 6;
    if (t + 1 < nt) {
      const bf16* kg = kg0 + (size_t)(k0 + 64) * 1024;
      const bf16* vg = vg0 + (k0 + 64);
      gl16(kg, &Ks[cur ^ 1][tid * 8]);
      gl16(kg + (size_t)32 * 1024, &Ks[cur ^ 1][2048 + tid * 8]);
      gl16(vg, &Vs[cur ^ 1][tid * 8]);
      gl16(vg + (size_t)32 * kvpad, &Vs[cur ^ 1][2048 + tid * 8]);
    }
    const bf16* Kc = &Ks[cur][0];
    const bf16* Vc = &Vs[cur][0];

    f32x4 sacc[4];
#pragma unroll
    for (int ni = 0; ni < 4; ++ni)
#pragma unroll
      for (int r = 0; r < 4; ++r) sacc[ni][r] = 0.0f;
#pragma unroll
    for (int ni = 0; ni < 4; ++ni) {
      int krow = ni * 16 + l15;
      int sw = (krow & 7) << 3;
      bf16x8 bk0 = *(const bf16x8*)&Kc[krow * 64 + ((quad * 8) ^ sw)];
      bf16x8 bk1 = *(const bf16x8*)&Kc[krow * 64 + ((32 + quad * 8) ^ sw)];
      sacc[ni] = MFMA(aq0, bk0, sacc[ni]);
      sacc[ni] = MFMA(aq1, bk1, sacc[ni]);
    }
    if (k0 + 64 > Sk) {
#pragma unroll
      for (int ni = 0; ni < 4; ++ni) {
        bool oob = (k0 + ni * 16 + l15 >= Sk);
#pragma unroll
        for (int r = 0; r < 4; ++r)
          if (oob) sacc[ni][r] = -1e30f;
      }
    }
    float alpha[4], mC[4];
#pragma unroll
    for (int r = 0; r < 4; ++r) {
      float v = fmaxf(fmaxf(sacc[0][r], sacc[1][r]), fmaxf(sacc[2][r], sacc[3][r]));
#pragma unroll
      for (int off = 1; off < 16; off <<= 1) v = fmaxf(v, __shfl_xor(v, off));
      float mn = fmaxf(m_r[r], v);
      alpha[r] = __builtin_amdgcn_exp2f((m_r[r] - mn) * CSC);
      m_r[r] = mn;
      mC[r] = mn * CSC;
    }
    bf16* ps = &Ps[wave][0];
#pragma unroll
    for (int ni = 0; ni < 4; ++ni) {
      int col = ni * 16 + l15;
#pragma unroll
      for (int r = 0; r < 4; ++r) {
        int prow = quad * 4 + r;
        ps[prow * 64 + (col ^ ((prow & 7) << 3))] =
            (bf16)__builtin_amdgcn_exp2f(sacc[ni][r] * CSC - mC[r]);
      }
    }
    int swp = (l15 & 7) << 3;
    bf16x8 ap0 = *(const bf16x8*)&ps[l15 * 64 + ((quad * 8) ^ swp)];
    bf16x8 ap1 = *(const bf16x8*)&ps[l15 * 64 + ((32 + quad * 8) ^ swp)];
    f32x4 psum;
#pragma unroll
    for (int r = 0; r < 4; ++r) psum[r] = 0.0f;
    psum = MFMA(ap0, ones8, psum);
    psum = MFMA(ap1, ones8, psum);
#pragma unroll
    for (int r = 0; r < 4; ++r) l_r[r] = l_r[r] * alpha[r] + psum[r];
#pragma unroll
    for (int ni = 0; ni < 4; ++ni) {
#pragma unroll
      for (int r = 0; r < 4; ++r) acc_o[ni][r] *= alpha[r];
      int vrow = ni * 16 + l15;
      int sw = (vrow & 7) << 3;
      bf16x8 bv0 = *(const bf16x8*)&Vc[vrow * 64 + ((quad * 8) ^ sw)];
      bf16x8 bv1 = *(const bf16x8*)&Vc[vrow * 64 + ((32 + quad * 8) ^ sw)];
      acc_o[ni] = MFMA(ap0, bv0, acc_o[ni]);
      acc_o[ni] = MFMA(ap1, bv1, acc_o[ni]);
    }
    __syncthreads();
    cur ^= 1;
  }
#pragma unroll
  for (int ni = 0; ni < 4; ++ni)
#pragma unroll
    for (int r = 0; r < 4; ++r) {
      int q = qt * 64 + wave * 16 + quad * 4 + r;
      float ov = acc_o[ni][r] / l_r[r];
      O[(size_t)(b * Sq + q) * 1024 + h * 64 + ni * 16 + l15] = (bf16)ov;
    }
}

extern "C" void kernel_launch(void* const* d_in, const int* in_sizes, int n_in,
                              void* d_out, int out_size, void* d_ws, size_t ws_size,
                              hipStream_t stream) {
  (void)in_sizes; (void)n_in; (void)out_size; (void)ws_size;
  const float* x = (const float*)d_in[0];
  const float* ctx = (const float*)d_in[1];
  const float* ln1_g = (const float*)d_in[2];
  const float* ln1_b = (const float*)d_in[3];
  const float* ln2_g = (const float*)d_in[4];
  const float* ln2_b = (const float*)d_in[5];
  const float* ln3_g = (const float*)d_in[6];
  const float* ln3_b = (const float*)d_in[7];
  const float* a1_wq = (const float*)d_in[8];
  const float* a1_wk = (const float*)d_in[9];
  const float* a1_wv = (const float*)d_in[10];
  const float* a1_wo = (const float*)d_in[11];
  const float* a1_bo = (const float*)d_in[12];
  const float* a2_wq = (const float*)d_in[13];
  const float* a2_wk = (const float*)d_in[14];
  const float* a2_wv = (const float*)d_in[15];
  const float* a2_wo = (const float*)d_in[16];
  const float* a2_bo = (const float*)d_in[17];
  const float* ff_w1 = (const float*)d_in[18];
  const float* ff_b1 = (const float*)d_in[19];
  const float* ff_w2 = (const float*)d_in[20];
  const float* ff_b2 = (const float*)d_in[21];
  float* xout = (float*)d_out;

  const int M = 4 * 2048;  // 8192 rows
  char* ws = (char*)d_ws;
  size_t off = 0;
  auto alloc = [&](size_t elems) -> bf16* {
    bf16* p = (bf16*)(ws + off);
    off += ((elems * sizeof(bf16)) + 255) & ~(size_t)255;
    return p;
  };
  bf16* wqkv1t = alloc((size_t)3072 * 1024);  // fused QKV weights [3072][1024]
  bf16* wo1t = alloc((size_t)1024 * 1024);
  bf16* wq2t = alloc((size_t)1024 * 1024);
  bf16* wk2t = alloc((size_t)1024 * 768);
  bf16* wv2t = alloc((size_t)1024 * 768);
  bf16* wo2t = alloc((size_t)1024 * 1024);
  bf16* w1t = alloc((size_t)8192 * 1024);  // PERMUTED rows (u/g paired per 256)
  bf16* w2t = alloc((size_t)1024 * 4096);
  bf16* lnb = alloc((size_t)M * 1024);
  bf16* qb = alloc((size_t)M * 1024);  // qb,kb,vb consecutive: QKV segment scatter
  bf16* kb = alloc((size_t)M * 1024);
  bf16* vb = alloc((size_t)M * 1024);
  bf16* ab = alloc((size_t)M * 1024);
  bf16* ctxb = alloc((size_t)308 * 768);
  bf16* kcb = alloc((size_t)308 * 1024);
  bf16* vcb = alloc((size_t)308 * 1024);
  bf16* hgb = alloc((size_t)M * 4096);
  // Vt buffers alias hgb (attention phases finish before geglu writes hgb)
  bf16* vtb = hgb;
  bf16* vtcb = hgb + (size_t)4 * 16 * 64 * 2048;

  hipMemcpyAsync(xout, x, (size_t)M * 1024 * sizeof(float),
                 hipMemcpyDeviceToDevice, stream);

  // weights -> bf16 transposed (N x K)
  k_transpose_cvt<0><<<dim3(32, 32), 256, 0, stream>>>(a1_wq, wqkv1t, 1024, 1024);
  k_transpose_cvt<0><<<dim3(32, 32), 256, 0, stream>>>(a1_wk, wqkv1t + (size_t)1024 * 1024, 1024, 1024);
  k_transpose_cvt<0><<<dim3(32, 32), 256, 0, stream>>>(a1_wv, wqkv1t + (size_t)2048 * 1024, 1024, 1024);
  k_transpose_cvt<0><<<dim3(32, 32), 256, 0, stream>>>(a1_wo, wo1t, 1024, 1024);
  k_transpose_cvt<0><<<dim3(32, 32), 256, 0, stream>>>(a2_wq, wq2t, 1024, 1024);
  k_transpose_cvt<0><<<dim3(24, 32), 256, 0, stream>>>(a2_wk, wk2t, 768, 1024);
  k_transpose_cvt<0><<<dim3(24, 32), 256, 0, stream>>>(a2_wv, wv2t, 768, 1024);
  k_transpose_cvt<0><<<dim3(32, 32), 256, 0, stream>>>(a2_wo, wo2t, 1024, 1024);
  k_transpose_cvt<1><<<dim3(32, 256), 256, 0, stream>>>(ff_w1, w1t, 1024, 8192);
  k_transpose_cvt<0><<<dim3(128, 32), 256, 0, stream>>>(ff_w2, w2t, 4096, 1024);
  k_cvt<<<(308 * 768 + 255) / 256, 256, 0, stream>>>(ctx, ctxb, 308 * 768);

  // ---- self-attention ----
  k_layernorm<<<M, 256, 0, stream>>>(xout, ln1_g, ln1_b, lnb);
  k_gemm256<0><<<dim3(32, 12), 512, 0, stream>>>(lnb, wqkv1t, nullptr, qb, M, 1024);
  k_transpose_v<<<dim3(32, 16, 4), 256, 0, stream>>>(vb, vtb, 2048, 2048);
  k_flash<<<dim3(32, 16, 4), 256, 0, stream>>>(qb, kb, vtb, ab, 2048, 2048, 2048, 2048);
  k_gemm_bt<1><<<dim3(64, 8), 256, 0, stream>>>(ab, wo1t, a1_bo, xout, xout, M, 1024, 1024);

  // ---- cross-attention ----
  k_layernorm<<<M, 256, 0, stream>>>(xout, ln2_g, ln2_b, lnb);
  k_gemm_bt<0><<<dim3(64, 8), 256, 0, stream>>>(lnb, wq2t, nullptr, nullptr, qb, M, 1024, 1024);
  k_gemm_bt<0><<<dim3(3, 8), 256, 0, stream>>>(ctxb, wk2t, nullptr, nullptr, kcb, 308, 1024, 768);
  k_gemm_bt<0><<<dim3(3, 8), 256, 0, stream>>>(ctxb, wv2t, nullptr, nullptr, vcb, 308, 1024, 768);
  k_transpose_v<<<dim3(2, 16, 4), 256, 0, stream>>>(vcb, vtcb, 77, 128);
  k_flash<<<dim3(32, 16, 4), 256, 0, stream>>>(qb, kcb, vtcb, ab, 2048, 77, 77, 128);
  k_gemm_bt<1><<<dim3(64, 8), 256, 0, stream>>>(ab, wo2t, a2_bo, xout, xout, M, 1024, 1024);

  // ---- GeGLU feed-forward ----
  k_layernorm<<<M, 256, 0, stream>>>(xout, ln3_g, ln3_b, lnb);
  k_gemm256<1><<<dim3(32, 32), 512, 0, stream>>>(lnb, w1t, ff_b1, hgb, M, 1024);
  k_gemm_bt<1><<<dim3(64, 8), 256, 0, stream>>>(hgb, w2t, ff_b2, xout, xout, M, 1024, 4096);
}

// Round 5
// 872.760 us; speedup vs baseline: 1.0610x; 1.0610x over previous
//
#include <hip/hip_runtime.h>
#include <hip/hip_bf16.h>
#include <math.h>

typedef __bf16 bf16;
typedef __bf16 bf16x8 __attribute__((ext_vector_type(8)));
typedef float f32x4 __attribute__((ext_vector_type(4)));

#define MFMA(a, b, c) __builtin_amdgcn_mfma_f32_16x16x32_bf16((a), (b), (c), 0, 0, 0)

// async global->LDS, 16B per lane. LDS dest must be wave-uniform base + lane*16.
static __device__ __forceinline__ void gl16(const bf16* g, bf16* l) {
  __builtin_amdgcn_global_load_lds(
      (const __attribute__((address_space(1))) void*)g,
      (__attribute__((address_space(3))) void*)l, 16, 0, 0);
}

static __device__ __forceinline__ bf16x8 bzero8() {
  bf16x8 v;
#pragma unroll
  for (int i = 0; i < 8; ++i) v[i] = (bf16)0.0f;
  return v;
}

// ---------- W (K x N fp32, row-major) -> Wt (N x K bf16, row-major) ----------
__global__ void k_transpose_cvt(const float* __restrict__ W, bf16* __restrict__ Wt,
                                int K, int N) {
  __shared__ float tile[32][33];
  int k0 = blockIdx.x * 32, n0 = blockIdx.y * 32;
  int tx = threadIdx.x & 31, ty = threadIdx.x >> 5;
  for (int i = ty; i < 32; i += 8)
    tile[i][tx] = W[(size_t)(k0 + i) * N + (n0 + tx)];
  __syncthreads();
  for (int i = ty; i < 32; i += 8)
    Wt[(size_t)(n0 + i) * K + (k0 + tx)] = (bf16)tile[tx][i];
}

// ---------- V (rows x 1024 bf16, token-major) -> Vt[b][h][d][kvpad] ----------
__global__ void k_transpose_v(const bf16* __restrict__ V, bf16* __restrict__ Vt,
                              int rows, int kvpad) {
  __shared__ __attribute__((aligned(16))) bf16 tile[64][72];
  int t0 = blockIdx.x * 64, h = blockIdx.y, b = blockIdx.z;
  int t = threadIdx.x;
  int tr = t >> 2, c0 = (t & 3) * 16;
  int token = t0 + tr;
  bf16x8 a = bzero8(), bv = bzero8();
  if (token < rows) {
    const bf16* src = V + ((size_t)(b * rows + token)) * 1024 + h * 64 + c0;
    a = *(const bf16x8*)src;
    bv = *(const bf16x8*)(src + 8);
  }
  *(bf16x8*)&tile[tr][c0] = a;
  *(bf16x8*)&tile[tr][c0 + 8] = bv;
  __syncthreads();
  int d = t >> 2, tq = (t & 3) * 16;
  bf16x8 o1, o2;
#pragma unroll
  for (int i = 0; i < 8; ++i) { o1[i] = tile[tq + i][d]; o2[i] = tile[tq + 8 + i][d]; }
  bf16* dst = Vt + ((size_t)((b * 16 + h) * 64 + d)) * kvpad + t0 + tq;
  *(bf16x8*)dst = o1;
  *(bf16x8*)(dst + 8) = o2;
}

// ---------- fp32 -> bf16 flat convert ----------
__global__ void k_cvt(const float* __restrict__ in, bf16* __restrict__ out, int n) {
  int i = blockIdx.x * 256 + threadIdx.x;
  if (i < n) out[i] = (bf16)in[i];
}

// ---------- LayerNorm over D=1024, one block per row, bf16 out ----------
__global__ void k_layernorm(const float* __restrict__ x, const float* __restrict__ g,
                            const float* __restrict__ b, bf16* __restrict__ out) {
  int row = blockIdx.x;
  float4 v = ((const float4*)(x + (size_t)row * 1024))[threadIdx.x];
  float s = v.x + v.y + v.z + v.w;
  float ss = v.x * v.x + v.y * v.y + v.z * v.z + v.w * v.w;
#pragma unroll
  for (int off = 1; off < 64; off <<= 1) {
    s += __shfl_xor(s, off);
    ss += __shfl_xor(ss, off);
  }
  __shared__ float sm[4], sm2[4];
  int w = threadIdx.x >> 6;
  if ((threadIdx.x & 63) == 0) { sm[w] = s; sm2[w] = ss; }
  __syncthreads();
  s = sm[0] + sm[1] + sm[2] + sm[3];
  ss = sm2[0] + sm2[1] + sm2[2] + sm2[3];
  float mu = s * (1.0f / 1024.0f);
  float var = ss * (1.0f / 1024.0f) - mu * mu;
  float rs = rsqrtf(var + 1e-5f);
  float4 gg = ((const float4*)g)[threadIdx.x];
  float4 bb = ((const float4*)b)[threadIdx.x];
  bf16* o = out + (size_t)row * 1024 + threadIdx.x * 4;
  o[0] = (bf16)((v.x - mu) * rs * gg.x + bb.x);
  o[1] = (bf16)((v.y - mu) * rs * gg.y + bb.y);
  o[2] = (bf16)((v.z - mu) * rs * gg.z + bb.z);
  o[3] = (bf16)((v.w - mu) * rs * gg.w + bb.w);
}

// ---------- GEMM: C[M,N] = A[M,K] @ Bt[N,K]^T  (bf16 in, fp32 acc) ----------
// EPI 0: bf16 out, column-segment scatter: col seg s=col>>10 goes to buffer
//   Cp + s*segM*1024 at row-stride 1024 (fused QKV / fused ctx-KV; 128-col
//   tiles never cross a 1024 boundary so seg is block-uniform).
// EPI 1: fp32 out = acc + bias[col] + res[row*N+col].
template <int EPI>
__global__ __launch_bounds__(256, 2)
void k_gemm_bt(const bf16* __restrict__ A, const bf16* __restrict__ Bt,
               const float* __restrict__ bias, const float* __restrict__ res,
               void* __restrict__ Cp, int M, int N, int K, int segM) {
  __shared__ __attribute__((aligned(16))) bf16 As[128 * 32];
  __shared__ __attribute__((aligned(16))) bf16 Bs[128 * 32];
  int m0 = blockIdx.x * 128, n0 = blockIdx.y * 128;
  int tid = threadIdx.x, lane = tid & 63, wave = tid >> 6;
  int wm = (wave >> 1) * 64, wn = (wave & 1) * 64;
  int quad = lane >> 4, l15 = lane & 15;
  f32x4 acc[4][4];
#pragma unroll
  for (int i = 0; i < 4; ++i)
#pragma unroll
    for (int j = 0; j < 4; ++j)
#pragma unroll
      for (int r = 0; r < 4; ++r) acc[i][j][r] = 0.0f;
  int srow = wave * 16 + (lane >> 2), scol = (lane & 3) * 8;
  const bf16* ga = A + (size_t)(m0 + srow) * K + scol;
  const bf16* gb = Bt + (size_t)(n0 + srow) * K + scol;
  bf16* la = As + srow * 32 + scol;
  bf16* lb = Bs + srow * 32 + scol;
  for (int k0 = 0; k0 < K; k0 += 32) {
    gl16(ga, la);
    gl16(ga + (size_t)64 * K, la + 64 * 32);
    gl16(gb, lb);
    gl16(gb + (size_t)64 * K, lb + 64 * 32);
    ga += 32; gb += 32;
    __syncthreads();
    bf16x8 af[4], bfr[4];
#pragma unroll
    for (int i = 0; i < 4; ++i) af[i] = *(const bf16x8*)(&As[(wm + i * 16 + l15) * 32 + quad * 8]);
#pragma unroll
    for (int i = 0; i < 4; ++i) bfr[i] = *(const bf16x8*)(&Bs[(wn + i * 16 + l15) * 32 + quad * 8]);
#pragma unroll
    for (int mi = 0; mi < 4; ++mi)
#pragma unroll
      for (int ni = 0; ni < 4; ++ni)
        acc[mi][ni] = MFMA(af[mi], bfr[ni], acc[mi][ni]);
    __syncthreads();
  }
  if (EPI == 0) {
    bf16* outp = (bf16*)Cp + (size_t)(n0 >> 10) * segM * 1024;
    int cl0 = (n0 & 1023) + wn;
#pragma unroll
    for (int mi = 0; mi < 4; ++mi) {
#pragma unroll
      for (int r = 0; r < 4; ++r) {
        int row = m0 + wm + mi * 16 + quad * 4 + r;
        if (row >= M) continue;
#pragma unroll
        for (int ni = 0; ni < 4; ++ni)
          outp[(size_t)row * 1024 + cl0 + ni * 16 + l15] = (bf16)acc[mi][ni][r];
      }
    }
  } else {
#pragma unroll
    for (int mi = 0; mi < 4; ++mi) {
#pragma unroll
      for (int r = 0; r < 4; ++r) {
        int row = m0 + wm + mi * 16 + quad * 4 + r;
        if (row >= M) continue;
#pragma unroll
        for (int ni = 0; ni < 4; ++ni) {
          int col = n0 + wn + ni * 16 + l15;
          ((float*)Cp)[(size_t)row * N + col] =
              acc[mi][ni][r] + bias[col] + res[(size_t)row * N + col];
        }
      }
    }
  }
}

// ---------- GEMM + GeGLU, 128x128 tile, dual accumulators ----------
__global__ __launch_bounds__(256, 2)
void k_gemm_geglu(const bf16* __restrict__ A, const bf16* __restrict__ W1t,
                  const float* __restrict__ b1, bf16* __restrict__ Hg,
                  int M, int K) {
  __shared__ __attribute__((aligned(16))) bf16 As[128 * 32];
  __shared__ __attribute__((aligned(16))) bf16 Bu[128 * 32];
  __shared__ __attribute__((aligned(16))) bf16 Bg[128 * 32];
  const int N = 4096;
  int m0 = blockIdx.x * 128, n0 = blockIdx.y * 128;
  int tid = threadIdx.x, lane = tid & 63, wave = tid >> 6;
  int wm = (wave >> 1) * 64, wn = (wave & 1) * 64;
  int quad = lane >> 4, l15 = lane & 15;
  f32x4 accu[4][4], accg[4][4];
#pragma unroll
  for (int i = 0; i < 4; ++i)
#pragma unroll
    for (int j = 0; j < 4; ++j)
#pragma unroll
      for (int r = 0; r < 4; ++r) { accu[i][j][r] = 0.0f; accg[i][j][r] = 0.0f; }
  int srow = wave * 16 + (lane >> 2), scol = (lane & 3) * 8;
  const bf16* ga = A + (size_t)(m0 + srow) * K + scol;
  const bf16* gu = W1t + (size_t)(n0 + srow) * K + scol;
  const bf16* gg = W1t + (size_t)(n0 + srow + 4096) * K + scol;
  bf16* la = As + srow * 32 + scol;
  bf16* lu = Bu + srow * 32 + scol;
  bf16* lg = Bg + srow * 32 + scol;
  for (int k0 = 0; k0 < K; k0 += 32) {
    gl16(ga, la);
    gl16(ga + (size_t)64 * K, la + 64 * 32);
    gl16(gu, lu);
    gl16(gu + (size_t)64 * K, lu + 64 * 32);
    gl16(gg, lg);
    gl16(gg + (size_t)64 * K, lg + 64 * 32);
    ga += 32; gu += 32; gg += 32;
    __syncthreads();
    bf16x8 af[4], bu[4], bg[4];
#pragma unroll
    for (int i = 0; i < 4; ++i) af[i] = *(const bf16x8*)(&As[(wm + i * 16 + l15) * 32 + quad * 8]);
#pragma unroll
    for (int i = 0; i < 4; ++i) bu[i] = *(const bf16x8*)(&Bu[(wn + i * 16 + l15) * 32 + quad * 8]);
#pragma unroll
    for (int i = 0; i < 4; ++i) bg[i] = *(const bf16x8*)(&Bg[(wn + i * 16 + l15) * 32 + quad * 8]);
#pragma unroll
    for (int mi = 0; mi < 4; ++mi)
#pragma unroll
      for (int ni = 0; ni < 4; ++ni) {
        accu[mi][ni] = MFMA(af[mi], bu[ni], accu[mi][ni]);
        accg[mi][ni] = MFMA(af[mi], bg[ni], accg[mi][ni]);
      }
    __syncthreads();
  }
#pragma unroll
  for (int mi = 0; mi < 4; ++mi)
#pragma unroll
    for (int r = 0; r < 4; ++r) {
      int row = m0 + wm + mi * 16 + quad * 4 + r;
#pragma unroll
      for (int ni = 0; ni < 4; ++ni) {
        int col = n0 + wn + ni * 16 + l15;
        float u = accu[mi][ni][r] + b1[col];
        float g = accg[mi][ni][r] + b1[col + 4096];
        float ge = 0.5f * g * (1.0f + erff(g * 0.70710678118654752f));
        Hg[(size_t)row * N + col] = (bf16)(u * ge);
      }
    }
}

// ---------- Flash attention: 64 q-rows/block, 64-key chunks, pre-transposed V --
// K/V in XOR-swizzled LDS, double-buffered, one barrier/iter (round-0 design).
// T13 defer-max: skip O/l rescale when rowmax growth <= 44 raw (= 8 exp2 units,
// P bounded by 256; wave-uniform branch via __all).
#define CSC 0.18033688011112042f /* 0.125 * log2(e) */
__global__ __launch_bounds__(256, 4)
void k_flash(const bf16* __restrict__ Q, const bf16* __restrict__ Kb,
             const bf16* __restrict__ VtG, bf16* __restrict__ O,
             int Sq, int Sk, int kvrows, int kvpad) {
  __shared__ __attribute__((aligned(16))) bf16 Ks[2][64 * 64];
  __shared__ __attribute__((aligned(16))) bf16 Vs[2][64 * 64];  // Vs[d][key]
  __shared__ __attribute__((aligned(16))) bf16 Ps[4][16 * 64];
  int qt = blockIdx.x, h = blockIdx.y, b = blockIdx.z;
  int tid = threadIdx.x, lane = tid & 63, wave = tid >> 6;
  int quad = lane >> 4, l15 = lane & 15;
  const bf16* qsrc = Q + (size_t)(b * Sq + qt * 64 + wave * 16 + l15) * 1024 + h * 64 + quad * 8;
  bf16x8 aq0 = *(const bf16x8*)qsrc;
  bf16x8 aq1 = *(const bf16x8*)(qsrc + 32);
  bf16x8 ones8;
#pragma unroll
  for (int i = 0; i < 8; ++i) ones8[i] = (bf16)1.0f;

  float m_r[4], l_r[4];
  f32x4 acc_o[4];
#pragma unroll
  for (int r = 0; r < 4; ++r) { m_r[r] = -1e30f; l_r[r] = 0.0f; }
#pragma unroll
  for (int ni = 0; ni < 4; ++ni)
#pragma unroll
    for (int r = 0; r < 4; ++r) acc_o[ni][r] = 0.0f;

  int srow = tid >> 3;
  int scol = ((tid & 7) * 8) ^ ((srow & 7) << 3);
  const bf16* kg0 = Kb + (size_t)(b * kvrows + srow) * 1024 + h * 64 + scol;
  const bf16* vg0 = VtG + ((size_t)((b * 16 + h) * 64 + srow)) * kvpad + scol;

  int nt = (Sk + 63) >> 6;
  {
    gl16(kg0, &Ks[0][tid * 8]);
    gl16(kg0 + (size_t)32 * 1024, &Ks[0][2048 + tid * 8]);
    gl16(vg0, &Vs[0][tid * 8]);
    gl16(vg0 + (size_t)32 * kvpad, &Vs[0][2048 + tid * 8]);
  }
  __syncthreads();

  int cur = 0;
  for (int t = 0; t < nt; ++t) {
    int k0 = t << 6;
    if (t + 1 < nt) {
      const bf16* kg = kg0 + (size_t)(k0 + 64) * 1024;
      const bf16* vg = vg0 + (k0 + 64);
      gl16(kg, &Ks[cur ^ 1][tid * 8]);
      gl16(kg + (size_t)32 * 1024, &Ks[cur ^ 1][2048 + tid * 8]);
      gl16(vg, &Vs[cur ^ 1][tid * 8]);
      gl16(vg + (size_t)32 * kvpad, &Vs[cur ^ 1][2048 + tid * 8]);
    }
    const bf16* Kc = &Ks[cur][0];
    const bf16* Vc = &Vs[cur][0];

    f32x4 sacc[4];
#pragma unroll
    for (int ni = 0; ni < 4; ++ni)
#pragma unroll
      for (int r = 0; r < 4; ++r) sacc[ni][r] = 0.0f;
#pragma unroll
    for (int ni = 0; ni < 4; ++ni) {
      int krow = ni * 16 + l15;
      int sw = (krow & 7) << 3;
      bf16x8 bk0 = *(const bf16x8*)&Kc[krow * 64 + ((quad * 8) ^ sw)];
      bf16x8 bk1 = *(const bf16x8*)&Kc[krow * 64 + ((32 + quad * 8) ^ sw)];
      sacc[ni] = MFMA(aq0, bk0, sacc[ni]);
      sacc[ni] = MFMA(aq1, bk1, sacc[ni]);
    }
    if (k0 + 64 > Sk) {
#pragma unroll
      for (int ni = 0; ni < 4; ++ni) {
        bool oob = (k0 + ni * 16 + l15 >= Sk);
#pragma unroll
        for (int r = 0; r < 4; ++r)
          if (oob) sacc[ni][r] = -1e30f;
      }
    }
    // row maxima for this tile
    float v[4];
#pragma unroll
    for (int r = 0; r < 4; ++r) {
      float vv = fmaxf(fmaxf(sacc[0][r], sacc[1][r]), fmaxf(sacc[2][r], sacc[3][r]));
#pragma unroll
      for (int off = 1; off < 16; off <<= 1) vv = fmaxf(vv, __shfl_xor(vv, off));
      v[r] = vv;
    }
    // T13 defer-max: rescale only when growth exceeds threshold
    float grow = fmaxf(fmaxf(v[0] - m_r[0], v[1] - m_r[1]),
                       fmaxf(v[2] - m_r[2], v[3] - m_r[3]));
    if (!__all(grow <= 44.0f)) {
#pragma unroll
      for (int r = 0; r < 4; ++r) {
        float mn = fmaxf(m_r[r], v[r]);
        float al = __builtin_amdgcn_exp2f((m_r[r] - mn) * CSC);
        m_r[r] = mn;
        l_r[r] *= al;
#pragma unroll
        for (int ni = 0; ni < 4; ++ni) acc_o[ni][r] *= al;
      }
    }
    float mC[4];
#pragma unroll
    for (int r = 0; r < 4; ++r) mC[r] = m_r[r] * CSC;
    bf16* ps = &Ps[wave][0];
#pragma unroll
    for (int ni = 0; ni < 4; ++ni) {
      int col = ni * 16 + l15;
#pragma unroll
      for (int r = 0; r < 4; ++r) {
        int prow = quad * 4 + r;
        ps[prow * 64 + (col ^ ((prow & 7) << 3))] =
            (bf16)__builtin_amdgcn_exp2f(sacc[ni][r] * CSC - mC[r]);
      }
    }
    int swp = (l15 & 7) << 3;
    bf16x8 ap0 = *(const bf16x8*)&ps[l15 * 64 + ((quad * 8) ^ swp)];
    bf16x8 ap1 = *(const bf16x8*)&ps[l15 * 64 + ((32 + quad * 8) ^ swp)];
    f32x4 psum;
#pragma unroll
    for (int r = 0; r < 4; ++r) psum[r] = 0.0f;
    psum = MFMA(ap0, ones8, psum);
    psum = MFMA(ap1, ones8, psum);
#pragma unroll
    for (int r = 0; r < 4; ++r) l_r[r] += psum[r];
#pragma unroll
    for (int ni = 0; ni < 4; ++ni) {
      int vrow = ni * 16 + l15;
      int sw = (vrow & 7) << 3;
      bf16x8 bv0 = *(const bf16x8*)&Vc[vrow * 64 + ((quad * 8) ^ sw)];
      bf16x8 bv1 = *(const bf16x8*)&Vc[vrow * 64 + ((32 + quad * 8) ^ sw)];
      acc_o[ni] = MFMA(ap0, bv0, acc_o[ni]);
      acc_o[ni] = MFMA(ap1, bv1, acc_o[ni]);
    }
    __syncthreads();
    cur ^= 1;
  }
#pragma unroll
  for (int ni = 0; ni < 4; ++ni)
#pragma unroll
    for (int r = 0; r < 4; ++r) {
      int q = qt * 64 + wave * 16 + quad * 4 + r;
      float ov = acc_o[ni][r] / l_r[r];
      O[(size_t)(b * Sq + q) * 1024 + h * 64 + ni * 16 + l15] = (bf16)ov;
    }
}

extern "C" void kernel_launch(void* const* d_in, const int* in_sizes, int n_in,
                              void* d_out, int out_size, void* d_ws, size_t ws_size,
                              hipStream_t stream) {
  (void)in_sizes; (void)n_in; (void)out_size; (void)ws_size;
  const float* x = (const float*)d_in[0];
  const float* ctx = (const float*)d_in[1];
  const float* ln1_g = (const float*)d_in[2];
  const float* ln1_b = (const float*)d_in[3];
  const float* ln2_g = (const float*)d_in[4];
  const float* ln2_b = (const float*)d_in[5];
  const float* ln3_g = (const float*)d_in[6];
  const float* ln3_b = (const float*)d_in[7];
  const float* a1_wq = (const float*)d_in[8];
  const float* a1_wk = (const float*)d_in[9];
  const float* a1_wv = (const float*)d_in[10];
  const float* a1_wo = (const float*)d_in[11];
  const float* a1_bo = (const float*)d_in[12];
  const float* a2_wq = (const float*)d_in[13];
  const float* a2_wk = (const float*)d_in[14];
  const float* a2_wv = (const float*)d_in[15];
  const float* a2_wo = (const float*)d_in[16];
  const float* a2_bo = (const float*)d_in[17];
  const float* ff_w1 = (const float*)d_in[18];
  const float* ff_b1 = (const float*)d_in[19];
  const float* ff_w2 = (const float*)d_in[20];
  const float* ff_b2 = (const float*)d_in[21];
  float* xout = (float*)d_out;

  const int M = 4 * 2048;  // 8192 rows
  char* ws = (char*)d_ws;
  size_t off = 0;
  auto alloc = [&](size_t elems) -> bf16* {
    bf16* p = (bf16*)(ws + off);
    off += ((elems * sizeof(bf16)) + 255) & ~(size_t)255;
    return p;
  };
  bf16* wqkv1t = alloc((size_t)3072 * 1024);  // fused self QKV weights
  bf16* wo1t = alloc((size_t)1024 * 1024);
  bf16* wq2t = alloc((size_t)1024 * 1024);
  bf16* wkv2t = alloc((size_t)2048 * 768);    // fused ctx K/V weights
  bf16* wo2t = alloc((size_t)1024 * 1024);
  bf16* w1t = alloc((size_t)8192 * 1024);
  bf16* w2t = alloc((size_t)1024 * 4096);
  bf16* lnb = alloc((size_t)M * 1024);
  bf16* qb = alloc((size_t)M * 1024);  // qb,kb,vb contiguous: QKV segment scatter
  bf16* kb = alloc((size_t)M * 1024);
  bf16* vb = alloc((size_t)M * 1024);
  bf16* ab = alloc((size_t)M * 1024);
  bf16* ctxb = alloc((size_t)308 * 768);
  bf16* kcb = alloc((size_t)308 * 1024);  // kcb,vcb contiguous: ctx KV scatter
  bf16* vcb = alloc((size_t)308 * 1024);
  bf16* hgb = alloc((size_t)M * 4096);
  // Vt buffers alias hgb (attention phases finish before geglu writes hgb)
  bf16* vtb = hgb;
  bf16* vtcb = hgb + (size_t)4 * 16 * 64 * 2048;

  hipMemcpyAsync(xout, x, (size_t)M * 1024 * sizeof(float),
                 hipMemcpyDeviceToDevice, stream);

  // weights -> bf16 transposed (N x K)
  k_transpose_cvt<<<dim3(32, 32), 256, 0, stream>>>(a1_wq, wqkv1t, 1024, 1024);
  k_transpose_cvt<<<dim3(32, 32), 256, 0, stream>>>(a1_wk, wqkv1t + (size_t)1024 * 1024, 1024, 1024);
  k_transpose_cvt<<<dim3(32, 32), 256, 0, stream>>>(a1_wv, wqkv1t + (size_t)2048 * 1024, 1024, 1024);
  k_transpose_cvt<<<dim3(32, 32), 256, 0, stream>>>(a1_wo, wo1t, 1024, 1024);
  k_transpose_cvt<<<dim3(32, 32), 256, 0, stream>>>(a2_wq, wq2t, 1024, 1024);
  k_transpose_cvt<<<dim3(24, 32), 256, 0, stream>>>(a2_wk, wkv2t, 768, 1024);
  k_transpose_cvt<<<dim3(24, 32), 256, 0, stream>>>(a2_wv, wkv2t + (size_t)1024 * 768, 768, 1024);
  k_transpose_cvt<<<dim3(32, 32), 256, 0, stream>>>(a2_wo, wo2t, 1024, 1024);
  k_transpose_cvt<<<dim3(32, 256), 256, 0, stream>>>(ff_w1, w1t, 1024, 8192);
  k_transpose_cvt<<<dim3(128, 32), 256, 0, stream>>>(ff_w2, w2t, 4096, 1024);
  k_cvt<<<(308 * 768 + 255) / 256, 256, 0, stream>>>(ctx, ctxb, 308 * 768);

  // ---- self-attention ----
  k_layernorm<<<M, 256, 0, stream>>>(xout, ln1_g, ln1_b, lnb);
  k_gemm_bt<0><<<dim3(64, 24), 256, 0, stream>>>(lnb, wqkv1t, nullptr, nullptr, qb, M, 3072, 1024, M);
  k_transpose_v<<<dim3(32, 16, 4), 256, 0, stream>>>(vb, vtb, 2048, 2048);
  k_flash<<<dim3(32, 16, 4), 256, 0, stream>>>(qb, kb, vtb, ab, 2048, 2048, 2048, 2048);
  k_gemm_bt<1><<<dim3(64, 8), 256, 0, stream>>>(ab, wo1t, a1_bo, xout, xout, M, 1024, 1024, 0);

  // ---- cross-attention ----
  k_layernorm<<<M, 256, 0, stream>>>(xout, ln2_g, ln2_b, lnb);
  k_gemm_bt<0><<<dim3(64, 8), 256, 0, stream>>>(lnb, wq2t, nullptr, nullptr, qb, M, 1024, 1024, 0);
  k_gemm_bt<0><<<dim3(3, 16), 256, 0, stream>>>(ctxb, wkv2t, nullptr, nullptr, kcb, 308, 2048, 768, 308);
  k_transpose_v<<<dim3(2, 16, 4), 256, 0, stream>>>(vcb, vtcb, 77, 128);
  k_flash<<<dim3(32, 16, 4), 256, 0, stream>>>(qb, kcb, vtcb, ab, 2048, 77, 77, 128);
  k_gemm_bt<1><<<dim3(64, 8), 256, 0, stream>>>(ab, wo2t, a2_bo, xout, xout, M, 1024, 1024, 0);

  // ---- GeGLU feed-forward ----
  k_layernorm<<<M, 256, 0, stream>>>(xout, ln3_g, ln3_b, lnb);
  k_gemm_geglu<<<dim3(64, 32), 256, 0, stream>>>(lnb, w1t, ff_b1, hgb, M, 1024);
  k_gemm_bt<1><<<dim3(64, 8), 256, 0, stream>>>(hgb, w2t, ff_b2, xout, xout, M, 1024, 4096, 0);
}

// Round 6
// 801.685 us; speedup vs baseline: 1.1550x; 1.0887x over previous
//
#include <hip/hip_runtime.h>
#include <hip/hip_bf16.h>
#include <math.h>

typedef __bf16 bf16;
typedef __bf16 bf16x8 __attribute__((ext_vector_type(8)));
typedef float f32x4 __attribute__((ext_vector_type(4)));

#define MFMA(a, b, c) __builtin_amdgcn_mfma_f32_16x16x32_bf16((a), (b), (c), 0, 0, 0)

// async global->LDS, 16B per lane. LDS dest must be wave-uniform base + lane*16.
static __device__ __forceinline__ void gl16(const bf16* g, bf16* l) {
  __builtin_amdgcn_global_load_lds(
      (const __attribute__((address_space(1))) void*)g,
      (__attribute__((address_space(3))) void*)l, 16, 0, 0);
}

static __device__ __forceinline__ bf16x8 bzero8() {
  bf16x8 v;
#pragma unroll
  for (int i = 0; i < 8; ++i) v[i] = (bf16)0.0f;
  return v;
}

// ---------- W (K x N fp32, row-major) -> Wt (N x K bf16, row-major) ----------
__global__ void k_transpose_cvt(const float* __restrict__ W, bf16* __restrict__ Wt,
                                int K, int N) {
  __shared__ float tile[32][33];
  int k0 = blockIdx.x * 32, n0 = blockIdx.y * 32;
  int tx = threadIdx.x & 31, ty = threadIdx.x >> 5;
  for (int i = ty; i < 32; i += 8)
    tile[i][tx] = W[(size_t)(k0 + i) * N + (n0 + tx)];
  __syncthreads();
  for (int i = ty; i < 32; i += 8)
    Wt[(size_t)(n0 + i) * K + (k0 + tx)] = (bf16)tile[tx][i];
}

// ---------- V (rows x 1024 bf16, token-major) -> Vt[b][h][d][kvpad] ----------
__global__ void k_transpose_v(const bf16* __restrict__ V, bf16* __restrict__ Vt,
                              int rows, int kvpad) {
  __shared__ __attribute__((aligned(16))) bf16 tile[64][72];
  int t0 = blockIdx.x * 64, h = blockIdx.y, b = blockIdx.z;
  int t = threadIdx.x;
  int tr = t >> 2, c0 = (t & 3) * 16;
  int token = t0 + tr;
  bf16x8 a = bzero8(), bv = bzero8();
  if (token < rows) {
    const bf16* src = V + ((size_t)(b * rows + token)) * 1024 + h * 64 + c0;
    a = *(const bf16x8*)src;
    bv = *(const bf16x8*)(src + 8);
  }
  *(bf16x8*)&tile[tr][c0] = a;
  *(bf16x8*)&tile[tr][c0 + 8] = bv;
  __syncthreads();
  int d = t >> 2, tq = (t & 3) * 16;
  bf16x8 o1, o2;
#pragma unroll
  for (int i = 0; i < 8; ++i) { o1[i] = tile[tq + i][d]; o2[i] = tile[tq + 8 + i][d]; }
  bf16* dst = Vt + ((size_t)((b * 16 + h) * 64 + d)) * kvpad + t0 + tq;
  *(bf16x8*)dst = o1;
  *(bf16x8*)(dst + 8) = o2;
}

// ---------- fp32 -> bf16 flat convert ----------
__global__ void k_cvt(const float* __restrict__ in, bf16* __restrict__ out, int n) {
  int i = blockIdx.x * 256 + threadIdx.x;
  if (i < n) out[i] = (bf16)in[i];
}

// ---------- LayerNorm over D=1024, one block per row, bf16 out ----------
__global__ void k_layernorm(const float* __restrict__ x, const float* __restrict__ g,
                            const float* __restrict__ b, bf16* __restrict__ out) {
  int row = blockIdx.x;
  float4 v = ((const float4*)(x + (size_t)row * 1024))[threadIdx.x];
  float s = v.x + v.y + v.z + v.w;
  float ss = v.x * v.x + v.y * v.y + v.z * v.z + v.w * v.w;
#pragma unroll
  for (int off = 1; off < 64; off <<= 1) {
    s += __shfl_xor(s, off);
    ss += __shfl_xor(ss, off);
  }
  __shared__ float sm[4], sm2[4];
  int w = threadIdx.x >> 6;
  if ((threadIdx.x & 63) == 0) { sm[w] = s; sm2[w] = ss; }
  __syncthreads();
  s = sm[0] + sm[1] + sm[2] + sm[3];
  ss = sm2[0] + sm2[1] + sm2[2] + sm2[3];
  float mu = s * (1.0f / 1024.0f);
  float var = ss * (1.0f / 1024.0f) - mu * mu;
  float rs = rsqrtf(var + 1e-5f);
  float4 gg = ((const float4*)g)[threadIdx.x];
  float4 bb = ((const float4*)b)[threadIdx.x];
  bf16* o = out + (size_t)row * 1024 + threadIdx.x * 4;
  o[0] = (bf16)((v.x - mu) * rs * gg.x + bb.x);
  o[1] = (bf16)((v.y - mu) * rs * gg.y + bb.y);
  o[2] = (bf16)((v.z - mu) * rs * gg.z + bb.z);
  o[3] = (bf16)((v.w - mu) * rs * gg.w + bb.w);
}

// ---------- GEMM: C[M,N] = A[M,K] @ Bt[N,K]^T  (bf16 in, fp32 acc) ----------
// BK=64 m97-family loop: half the barrier/vmcnt-drain count of BK=32, double
// the MFMA per drain. 128B LDS rows are a 16-way bank conflict (G4), so tiles
// are XOR-swizzled (col ^= (row&7)<<3): linear gl16 dest + inverse-swizzled
// global source (rule #21, same pattern as k_flash); read XOR folds to the
// lane constant (l15&7)<<3. LDS 32KB -> 3 blocks/CU.
// EPI 0: bf16 out, column-segment scatter (col>>10 -> segment buffer, block-
//   uniform since 128-col tiles never cross a 1024 boundary).
// EPI 1: fp32 out = acc + bias[col] + res[row*N+col].
template <int EPI>
__global__ __launch_bounds__(256, 3)
void k_gemm_bt(const bf16* __restrict__ A, const bf16* __restrict__ Bt,
               const float* __restrict__ bias, const float* __restrict__ res,
               void* __restrict__ Cp, int M, int N, int K, int segM) {
  __shared__ __attribute__((aligned(16))) bf16 As[128 * 64];
  __shared__ __attribute__((aligned(16))) bf16 Bs[128 * 64];
  int m0 = blockIdx.x * 128, n0 = blockIdx.y * 128;
  int tid = threadIdx.x, lane = tid & 63, wave = tid >> 6;
  int wm = (wave >> 1) * 64, wn = (wave & 1) * 64;
  int quad = lane >> 4, l15 = lane & 15;
  int rsw = (l15 & 7) << 3;  // read-side swizzle, lane-constant (row&7 == l15&7)
  f32x4 acc[4][4];
#pragma unroll
  for (int i = 0; i < 4; ++i)
#pragma unroll
    for (int j = 0; j < 4; ++j)
#pragma unroll
      for (int r = 0; r < 4; ++r) acc[i][j][r] = 0.0f;
  // staging: 8 threads/row cover 64 cols; 4 rounds cover rows +0/+32/+64/+96.
  int srow = tid >> 3;
  int scol = ((tid & 7) * 8) ^ ((srow & 7) << 3);  // (srow+32r)&7 == srow&7
  int lofs = tid * 8;                              // linear dest, 2048 elems/round
  const bf16* ga = A + (size_t)(m0 + srow) * K + scol;
  const bf16* gb = Bt + (size_t)(n0 + srow) * K + scol;
  for (int k0 = 0; k0 < K; k0 += 64) {
#pragma unroll
    for (int r = 0; r < 4; ++r) {
      gl16(ga + (size_t)(32 * r) * K + k0, &As[r * 2048 + lofs]);
      gl16(gb + (size_t)(32 * r) * K + k0, &Bs[r * 2048 + lofs]);
    }
    __syncthreads();
#pragma unroll
    for (int kk = 0; kk < 2; ++kk) {
      bf16x8 af[4], bfr[4];
#pragma unroll
      for (int i = 0; i < 4; ++i)
        af[i] = *(const bf16x8*)(&As[(wm + i * 16 + l15) * 64 + ((kk * 32 + quad * 8) ^ rsw)]);
#pragma unroll
      for (int i = 0; i < 4; ++i)
        bfr[i] = *(const bf16x8*)(&Bs[(wn + i * 16 + l15) * 64 + ((kk * 32 + quad * 8) ^ rsw)]);
#pragma unroll
      for (int mi = 0; mi < 4; ++mi)
#pragma unroll
        for (int ni = 0; ni < 4; ++ni)
          acc[mi][ni] = MFMA(af[mi], bfr[ni], acc[mi][ni]);
    }
    __syncthreads();
  }
  if (EPI == 0) {
    bf16* outp = (bf16*)Cp + (size_t)(n0 >> 10) * segM * 1024;
    int cl0 = (n0 & 1023) + wn;
#pragma unroll
    for (int mi = 0; mi < 4; ++mi) {
#pragma unroll
      for (int r = 0; r < 4; ++r) {
        int row = m0 + wm + mi * 16 + quad * 4 + r;
        if (row >= M) continue;
#pragma unroll
        for (int ni = 0; ni < 4; ++ni)
          outp[(size_t)row * 1024 + cl0 + ni * 16 + l15] = (bf16)acc[mi][ni][r];
      }
    }
  } else {
#pragma unroll
    for (int mi = 0; mi < 4; ++mi) {
#pragma unroll
      for (int r = 0; r < 4; ++r) {
        int row = m0 + wm + mi * 16 + quad * 4 + r;
        if (row >= M) continue;
#pragma unroll
        for (int ni = 0; ni < 4; ++ni) {
          int col = n0 + wn + ni * 16 + l15;
          ((float*)Cp)[(size_t)row * N + col] =
              acc[mi][ni][r] + bias[col] + res[(size_t)row * N + col];
        }
      }
    }
  }
}

// ---------- GEMM + GeGLU, 128x128 tile, dual accumulators ----------
// Same BK=64 + XOR-swizzle loop; per-kk fragment loads keep VGPR flat.
__global__ __launch_bounds__(256, 2)
void k_gemm_geglu(const bf16* __restrict__ A, const bf16* __restrict__ W1t,
                  const float* __restrict__ b1, bf16* __restrict__ Hg,
                  int M, int K) {
  __shared__ __attribute__((aligned(16))) bf16 As[128 * 64];
  __shared__ __attribute__((aligned(16))) bf16 Bu[128 * 64];
  __shared__ __attribute__((aligned(16))) bf16 Bg[128 * 64];
  const int N = 4096;
  int m0 = blockIdx.x * 128, n0 = blockIdx.y * 128;
  int tid = threadIdx.x, lane = tid & 63, wave = tid >> 6;
  int wm = (wave >> 1) * 64, wn = (wave & 1) * 64;
  int quad = lane >> 4, l15 = lane & 15;
  int rsw = (l15 & 7) << 3;
  f32x4 accu[4][4], accg[4][4];
#pragma unroll
  for (int i = 0; i < 4; ++i)
#pragma unroll
    for (int j = 0; j < 4; ++j)
#pragma unroll
      for (int r = 0; r < 4; ++r) { accu[i][j][r] = 0.0f; accg[i][j][r] = 0.0f; }
  int srow = tid >> 3;
  int scol = ((tid & 7) * 8) ^ ((srow & 7) << 3);
  int lofs = tid * 8;
  const bf16* ga = A + (size_t)(m0 + srow) * K + scol;
  const bf16* gu = W1t + (size_t)(n0 + srow) * K + scol;
  const bf16* gg = W1t + (size_t)(n0 + srow + 4096) * K + scol;
  for (int k0 = 0; k0 < K; k0 += 64) {
#pragma unroll
    for (int r = 0; r < 4; ++r) {
      gl16(ga + (size_t)(32 * r) * K + k0, &As[r * 2048 + lofs]);
      gl16(gu + (size_t)(32 * r) * K + k0, &Bu[r * 2048 + lofs]);
      gl16(gg + (size_t)(32 * r) * K + k0, &Bg[r * 2048 + lofs]);
    }
    __syncthreads();
#pragma unroll
    for (int kk = 0; kk < 2; ++kk) {
      bf16x8 af[4], bu[4], bg[4];
#pragma unroll
      for (int i = 0; i < 4; ++i)
        af[i] = *(const bf16x8*)(&As[(wm + i * 16 + l15) * 64 + ((kk * 32 + quad * 8) ^ rsw)]);
#pragma unroll
      for (int i = 0; i < 4; ++i)
        bu[i] = *(const bf16x8*)(&Bu[(wn + i * 16 + l15) * 64 + ((kk * 32 + quad * 8) ^ rsw)]);
#pragma unroll
      for (int i = 0; i < 4; ++i)
        bg[i] = *(const bf16x8*)(&Bg[(wn + i * 16 + l15) * 64 + ((kk * 32 + quad * 8) ^ rsw)]);
#pragma unroll
      for (int mi = 0; mi < 4; ++mi)
#pragma unroll
        for (int ni = 0; ni < 4; ++ni) {
          accu[mi][ni] = MFMA(af[mi], bu[ni], accu[mi][ni]);
          accg[mi][ni] = MFMA(af[mi], bg[ni], accg[mi][ni]);
        }
    }
    __syncthreads();
  }
#pragma unroll
  for (int mi = 0; mi < 4; ++mi)
#pragma unroll
    for (int r = 0; r < 4; ++r) {
      int row = m0 + wm + mi * 16 + quad * 4 + r;
#pragma unroll
      for (int ni = 0; ni < 4; ++ni) {
        int col = n0 + wn + ni * 16 + l15;
        float u = accu[mi][ni][r] + b1[col];
        float g = accg[mi][ni][r] + b1[col + 4096];
        float ge = 0.5f * g * (1.0f + erff(g * 0.70710678118654752f));
        Hg[(size_t)row * N + col] = (bf16)(u * ge);
      }
    }
}

// ---------- Flash attention: 64 q-rows/block, 64-key chunks, pre-transposed V --
// K/V in XOR-swizzled LDS, double-buffered, one barrier/iter (round-0 design).
// T13 defer-max: skip O/l rescale when rowmax growth <= 44 raw (= 8 exp2 units,
// P bounded by 256; wave-uniform branch via __all).
#define CSC 0.18033688011112042f /* 0.125 * log2(e) */
__global__ __launch_bounds__(256, 4)
void k_flash(const bf16* __restrict__ Q, const bf16* __restrict__ Kb,
             const bf16* __restrict__ VtG, bf16* __restrict__ O,
             int Sq, int Sk, int kvrows, int kvpad) {
  __shared__ __attribute__((aligned(16))) bf16 Ks[2][64 * 64];
  __shared__ __attribute__((aligned(16))) bf16 Vs[2][64 * 64];  // Vs[d][key]
  __shared__ __attribute__((aligned(16))) bf16 Ps[4][16 * 64];
  int qt = blockIdx.x, h = blockIdx.y, b = blockIdx.z;
  int tid = threadIdx.x, lane = tid & 63, wave = tid >> 6;
  int quad = lane >> 4, l15 = lane & 15;
  const bf16* qsrc = Q + (size_t)(b * Sq + qt * 64 + wave * 16 + l15) * 1024 + h * 64 + quad * 8;
  bf16x8 aq0 = *(const bf16x8*)qsrc;
  bf16x8 aq1 = *(const bf16x8*)(qsrc + 32);
  bf16x8 ones8;
#pragma unroll
  for (int i = 0; i < 8; ++i) ones8[i] = (bf16)1.0f;

  float m_r[4], l_r[4];
  f32x4 acc_o[4];
#pragma unroll
  for (int r = 0; r < 4; ++r) { m_r[r] = -1e30f; l_r[r] = 0.0f; }
#pragma unroll
  for (int ni = 0; ni < 4; ++ni)
#pragma unroll
    for (int r = 0; r < 4; ++r) acc_o[ni][r] = 0.0f;

  int srow = tid >> 3;
  int scol = ((tid & 7) * 8) ^ ((srow & 7) << 3);
  const bf16* kg0 = Kb + (size_t)(b * kvrows + srow) * 1024 + h * 64 + scol;
  const bf16* vg0 = VtG + ((size_t)((b * 16 + h) * 64 + srow)) * kvpad + scol;

  int nt = (Sk + 63) >> 6;
  {
    gl16(kg0, &Ks[0][tid * 8]);
    gl16(kg0 + (size_t)32 * 1024, &Ks[0][2048 + tid * 8]);
    gl16(vg0, &Vs[0][tid * 8]);
    gl16(vg0 + (size_t)32 * kvpad, &Vs[0][2048 + tid * 8]);
  }
  __syncthreads();

  int cur = 0;
  for (int t = 0; t < nt; ++t) {
    int k0 = t << 6;
    if (t + 1 < nt) {
      const bf16* kg = kg0 + (size_t)(k0 + 64) * 1024;
      const bf16* vg = vg0 + (k0 + 64);
      gl16(kg, &Ks[cur ^ 1][tid * 8]);
      gl16(kg + (size_t)32 * 1024, &Ks[cur ^ 1][2048 + tid * 8]);
      gl16(vg, &Vs[cur ^ 1][tid * 8]);
      gl16(vg + (size_t)32 * kvpad, &Vs[cur ^ 1][2048 + tid * 8]);
    }
    const bf16* Kc = &Ks[cur][0];
    const bf16* Vc = &Vs[cur][0];

    f32x4 sacc[4];
#pragma unroll
    for (int ni = 0; ni < 4; ++ni)
#pragma unroll
      for (int r = 0; r < 4; ++r) sacc[ni][r] = 0.0f;
#pragma unroll
    for (int ni = 0; ni < 4; ++ni) {
      int krow = ni * 16 + l15;
      int sw = (krow & 7) << 3;
      bf16x8 bk0 = *(const bf16x8*)&Kc[krow * 64 + ((quad * 8) ^ sw)];
      bf16x8 bk1 = *(const bf16x8*)&Kc[krow * 64 + ((32 + quad * 8) ^ sw)];
      sacc[ni] = MFMA(aq0, bk0, sacc[ni]);
      sacc[ni] = MFMA(aq1, bk1, sacc[ni]);
    }
    if (k0 + 64 > Sk) {
#pragma unroll
      for (int ni = 0; ni < 4; ++ni) {
        bool oob = (k0 + ni * 16 + l15 >= Sk);
#pragma unroll
        for (int r = 0; r < 4; ++r)
          if (oob) sacc[ni][r] = -1e30f;
      }
    }
    // row maxima for this tile
    float v[4];
#pragma unroll
    for (int r = 0; r < 4; ++r) {
      float vv = fmaxf(fmaxf(sacc[0][r], sacc[1][r]), fmaxf(sacc[2][r], sacc[3][r]));
#pragma unroll
      for (int off = 1; off < 16; off <<= 1) vv = fmaxf(vv, __shfl_xor(vv, off));
      v[r] = vv;
    }
    // T13 defer-max: rescale only when growth exceeds threshold
    float grow = fmaxf(fmaxf(v[0] - m_r[0], v[1] - m_r[1]),
                       fmaxf(v[2] - m_r[2], v[3] - m_r[3]));
    if (!__all(grow <= 44.0f)) {
#pragma unroll
      for (int r = 0; r < 4; ++r) {
        float mn = fmaxf(m_r[r], v[r]);
        float al = __builtin_amdgcn_exp2f((m_r[r] - mn) * CSC);
        m_r[r] = mn;
        l_r[r] *= al;
#pragma unroll
        for (int ni = 0; ni < 4; ++ni) acc_o[ni][r] *= al;
      }
    }
    float mC[4];
#pragma unroll
    for (int r = 0; r < 4; ++r) mC[r] = m_r[r] * CSC;
    bf16* ps = &Ps[wave][0];
#pragma unroll
    for (int ni = 0; ni < 4; ++ni) {
      int col = ni * 16 + l15;
#pragma unroll
      for (int r = 0; r < 4; ++r) {
        int prow = quad * 4 + r;
        ps[prow * 64 + (col ^ ((prow & 7) << 3))] =
            (bf16)__builtin_amdgcn_exp2f(sacc[ni][r] * CSC - mC[r]);
      }
    }
    int swp = (l15 & 7) << 3;
    bf16x8 ap0 = *(const bf16x8*)&ps[l15 * 64 + ((quad * 8) ^ swp)];
    bf16x8 ap1 = *(const bf16x8*)&ps[l15 * 64 + ((32 + quad * 8) ^ swp)];
    f32x4 psum;
#pragma unroll
    for (int r = 0; r < 4; ++r) psum[r] = 0.0f;
    psum = MFMA(ap0, ones8, psum);
    psum = MFMA(ap1, ones8, psum);
#pragma unroll
    for (int r = 0; r < 4; ++r) l_r[r] += psum[r];
#pragma unroll
    for (int ni = 0; ni < 4; ++ni) {
      int vrow = ni * 16 + l15;
      int sw = (vrow & 7) << 3;
      bf16x8 bv0 = *(const bf16x8*)&Vc[vrow * 64 + ((quad * 8) ^ sw)];
      bf16x8 bv1 = *(const bf16x8*)&Vc[vrow * 64 + ((32 + quad * 8) ^ sw)];
      acc_o[ni] = MFMA(ap0, bv0, acc_o[ni]);
      acc_o[ni] = MFMA(ap1, bv1, acc_o[ni]);
    }
    __syncthreads();
    cur ^= 1;
  }
#pragma unroll
  for (int ni = 0; ni < 4; ++ni)
#pragma unroll
    for (int r = 0; r < 4; ++r) {
      int q = qt * 64 + wave * 16 + quad * 4 + r;
      float ov = acc_o[ni][r] / l_r[r];
      O[(size_t)(b * Sq + q) * 1024 + h * 64 + ni * 16 + l15] = (bf16)ov;
    }
}

extern "C" void kernel_launch(void* const* d_in, const int* in_sizes, int n_in,
                              void* d_out, int out_size, void* d_ws, size_t ws_size,
                              hipStream_t stream) {
  (void)in_sizes; (void)n_in; (void)out_size; (void)ws_size;
  const float* x = (const float*)d_in[0];
  const float* ctx = (const float*)d_in[1];
  const float* ln1_g = (const float*)d_in[2];
  const float* ln1_b = (const float*)d_in[3];
  const float* ln2_g = (const float*)d_in[4];
  const float* ln2_b = (const float*)d_in[5];
  const float* ln3_g = (const float*)d_in[6];
  const float* ln3_b = (const float*)d_in[7];
  const float* a1_wq = (const float*)d_in[8];
  const float* a1_wk = (const float*)d_in[9];
  const float* a1_wv = (const float*)d_in[10];
  const float* a1_wo = (const float*)d_in[11];
  const float* a1_bo = (const float*)d_in[12];
  const float* a2_wq = (const float*)d_in[13];
  const float* a2_wk = (const float*)d_in[14];
  const float* a2_wv = (const float*)d_in[15];
  const float* a2_wo = (const float*)d_in[16];
  const float* a2_bo = (const float*)d_in[17];
  const float* ff_w1 = (const float*)d_in[18];
  const float* ff_b1 = (const float*)d_in[19];
  const float* ff_w2 = (const float*)d_in[20];
  const float* ff_b2 = (const float*)d_in[21];
  float* xout = (float*)d_out;

  const int M = 4 * 2048;  // 8192 rows
  char* ws = (char*)d_ws;
  size_t off = 0;
  auto alloc = [&](size_t elems) -> bf16* {
    bf16* p = (bf16*)(ws + off);
    off += ((elems * sizeof(bf16)) + 255) & ~(size_t)255;
    return p;
  };
  bf16* wqkv1t = alloc((size_t)3072 * 1024);  // fused self QKV weights
  bf16* wo1t = alloc((size_t)1024 * 1024);
  bf16* wq2t = alloc((size_t)1024 * 1024);
  bf16* wkv2t = alloc((size_t)2048 * 768);    // fused ctx K/V weights
  bf16* wo2t = alloc((size_t)1024 * 1024);
  bf16* w1t = alloc((size_t)8192 * 1024);
  bf16* w2t = alloc((size_t)1024 * 4096);
  bf16* lnb = alloc((size_t)M * 1024);
  bf16* qb = alloc((size_t)M * 1024);  // qb,kb,vb contiguous: QKV segment scatter
  bf16* kb = alloc((size_t)M * 1024);
  bf16* vb = alloc((size_t)M * 1024);
  bf16* ab = alloc((size_t)M * 1024);
  bf16* ctxb = alloc((size_t)308 * 768);
  bf16* kcb = alloc((size_t)308 * 1024);  // kcb,vcb contiguous: ctx KV scatter
  bf16* vcb = alloc((size_t)308 * 1024);
  bf16* hgb = alloc((size_t)M * 4096);
  // Vt buffers alias hgb (attention phases finish before geglu writes hgb)
  bf16* vtb = hgb;
  bf16* vtcb = hgb + (size_t)4 * 16 * 64 * 2048;

  hipMemcpyAsync(xout, x, (size_t)M * 1024 * sizeof(float),
                 hipMemcpyDeviceToDevice, stream);

  // weights -> bf16 transposed (N x K)
  k_transpose_cvt<<<dim3(32, 32), 256, 0, stream>>>(a1_wq, wqkv1t, 1024, 1024);
  k_transpose_cvt<<<dim3(32, 32), 256, 0, stream>>>(a1_wk, wqkv1t + (size_t)1024 * 1024, 1024, 1024);
  k_transpose_cvt<<<dim3(32, 32), 256, 0, stream>>>(a1_wv, wqkv1t + (size_t)2048 * 1024, 1024, 1024);
  k_transpose_cvt<<<dim3(32, 32), 256, 0, stream>>>(a1_wo, wo1t, 1024, 1024);
  k_transpose_cvt<<<dim3(32, 32), 256, 0, stream>>>(a2_wq, wq2t, 1024, 1024);
  k_transpose_cvt<<<dim3(24, 32), 256, 0, stream>>>(a2_wk, wkv2t, 768, 1024);
  k_transpose_cvt<<<dim3(24, 32), 256, 0, stream>>>(a2_wv, wkv2t + (size_t)1024 * 768, 768, 1024);
  k_transpose_cvt<<<dim3(32, 32), 256, 0, stream>>>(a2_wo, wo2t, 1024, 1024);
  k_transpose_cvt<<<dim3(32, 256), 256, 0, stream>>>(ff_w1, w1t, 1024, 8192);
  k_transpose_cvt<<<dim3(128, 32), 256, 0, stream>>>(ff_w2, w2t, 4096, 1024);
  k_cvt<<<(308 * 768 + 255) / 256, 256, 0, stream>>>(ctx, ctxb, 308 * 768);

  // ---- self-attention ----
  k_layernorm<<<M, 256, 0, stream>>>(xout, ln1_g, ln1_b, lnb);
  k_gemm_bt<0><<<dim3(64, 24), 256, 0, stream>>>(lnb, wqkv1t, nullptr, nullptr, qb, M, 3072, 1024, M);
  k_transpose_v<<<dim3(32, 16, 4), 256, 0, stream>>>(vb, vtb, 2048, 2048);
  k_flash<<<dim3(32, 16, 4), 256, 0, stream>>>(qb, kb, vtb, ab, 2048, 2048, 2048, 2048);
  k_gemm_bt<1><<<dim3(64, 8), 256, 0, stream>>>(ab, wo1t, a1_bo, xout, xout, M, 1024, 1024, 0);

  // ---- cross-attention ----
  k_layernorm<<<M, 256, 0, stream>>>(xout, ln2_g, ln2_b, lnb);
  k_gemm_bt<0><<<dim3(64, 8), 256, 0, stream>>>(lnb, wq2t, nullptr, nullptr, qb, M, 1024, 1024, 0);
  k_gemm_bt<0><<<dim3(3, 16), 256, 0, stream>>>(ctxb, wkv2t, nullptr, nullptr, kcb, 308, 2048, 768, 308);
  k_transpose_v<<<dim3(2, 16, 4), 256, 0, stream>>>(vcb, vtcb, 77, 128);
  k_flash<<<dim3(32, 16, 4), 256, 0, stream>>>(qb, kcb, vtcb, ab, 2048, 77, 77, 128);
  k_gemm_bt<1><<<dim3(64, 8), 256, 0, stream>>>(ab, wo2t, a2_bo, xout, xout, M, 1024, 1024, 0);

  // ---- GeGLU feed-forward ----
  k_layernorm<<<M, 256, 0, stream>>>(xout, ln3_g, ln3_b, lnb);
  k_gemm_geglu<<<dim3(64, 32), 256, 0, stream>>>(lnb, w1t, ff_b1, hgb, M, 1024);
  k_gemm_bt<1><<<dim3(64, 8), 256, 0, stream>>>(hgb, w2t, ff_b2, xout, xout, M, 1024, 4096, 0);
}